// Round 8
// baseline (375.918 us; speedup 1.0000x reference)
//
#include <hip/hip_runtime.h>
#include <math.h>

typedef unsigned short u16;
typedef __attribute__((ext_vector_type(4))) float f32x4;
typedef __bf16 bf16x8 __attribute__((ext_vector_type(8)));

#define NTOK 8192
#define DDIM 1024
#define NEXP 7
#define CAPC 2574      /* int(8192*2/7*1.1) */
#define CPAD 2688      /* 21*128 */
#define EBLK 1176      /* 7 experts * 21 mblk * 8 nblk */
#define TBLK 1688      /* + 64*8 shared blocks; 1688 = 8*211 exactly */
#define XCHK 211       /* blocks per XCD chunk */

__device__ inline float bf2f(u16 u) {
    union { unsigned int i; float f; } c; c.i = ((unsigned int)u) << 16; return c.f;
}
__device__ inline u16 f2bf(float f) {
    union { float f; unsigned int i; } c; c.f = f;
    unsigned int u = c.i;
    unsigned int r = (u + 0x7fffu + ((u >> 16) & 1u)) >> 16;
    return (u16)r;
}

__device__ inline void gl2lds16(const u16* g, const u16* l) {
    __builtin_amdgcn_global_load_lds(
        (const __attribute__((address_space(1))) unsigned int*)g,
        (__attribute__((address_space(3))) unsigned int*)l, 16, 0, 0);
}

// ---------------- guard: zero the output (ws_size-too-small diagnostic) ----------------
__global__ void k_zero(float* out, long n) {
    long i = (long)blockIdx.x * 256 + threadIdx.x;
    long stride = (long)gridDim.x * 256;
    for (; i < n; i += stride) out[i] = 0.f;
}

// ---------------- LDS-tiled transpose core (256 threads; used by !sep fallback) ----------------
__device__ inline void tile_transpose(const float* __restrict__ src, u16* __restrict__ dst,
                                      int k0, int n0, int tid, u16 (*tbuf)[256]) {
#pragma unroll
    for (int p = 0; p < 16; ++p) {
        int kl = p * 16 + (tid >> 4);
        int nl = (tid & 15) * 4;
        float4 v = *(const float4*)(src + (long)(k0 + kl) * 1024 + n0 + nl);
        int s = (tid & 7) << 3;
        int kx = kl ^ s;
        tbuf[nl + 0][kx] = f2bf(v.x);
        tbuf[nl + 1][kx] = f2bf(v.y);
        tbuf[nl + 2][kx] = f2bf(v.z);
        tbuf[nl + 3][kx] = f2bf(v.w);
    }
    __syncthreads();
#pragma unroll
    for (int q = 0; q < 8; ++q) {
        int nl = q * 8 + (tid >> 5);
        int kl = (tid & 31) * 8;
        int s = ((nl >> 2) & 7) << 3;
        const u16* pr = &tbuf[nl][kl ^ s];
        ushort4 a = *(const ushort4*)pr;
        ushort4 b = *(const ushort4*)(pr + 4);
        u16* pd = dst + (long)(n0 + nl) * 1024 + k0 + kl;
        *(ushort4*)pd = a;
        *(ushort4*)(pd + 4) = b;
    }
}

// ---------------- weight transpose phase 2 (fallback when !sep): set1 only ----------------
__global__ void k_transpose(const float* __restrict__ srcE, const float* __restrict__ srcS,
                            u16* __restrict__ Wt, u16* __restrict__ Wst) {
    __shared__ u16 tbuf[64][256];
    int bid = blockIdx.x, tid = threadIdx.x;
    int z = bid >> 6;
    int rem = bid & 63;
    int k0 = (rem >> 4) * 256;
    int n0 = (rem & 15) * 64;
    const float* src; u16* dst;
    if (z < 7) { src = srcE + (long)z * 1048576; dst = Wt + (long)z * 1048576; }
    else       { src = srcS;                     dst = Wst; }
    tile_transpose(src, dst, k0, n0, tid, tbuf);
}

// ========== k_front: ONE launch = router (blocks 0..1023) + weight transposes + inits ==========
// Router: logits (fp64) + x->bf16 + top-2/softmax tail + chunk-8 counts (identical math to r7).
// Transpose blocks (512 thr, 256k x 64n tile) and init blocks co-schedule with the router:
// BW-bound transpose overlaps compute-bound router instead of serializing behind a launch gap.
__global__ __launch_bounds__(512) void k_front(
    const float* __restrict__ x,
    const float* __restrict__ Wr, const float* __restrict__ Wn,
    const float* __restrict__ br, const float* __restrict__ bn,
    const float* __restrict__ noise,
    u16* __restrict__ xb,
    int* __restrict__ idx0, int* __restrict__ idx1,
    float* __restrict__ p0, float* __restrict__ p1,
    int* __restrict__ cnt8, double* __restrict__ sum8,
    int* __restrict__ slot_token, u16* __restrict__ zrow,
    const float* __restrict__ W1, const float* __restrict__ Ws1,
    u16* __restrict__ Wt, u16* __restrict__ Wst,
    const float* __restrict__ W2, const float* __restrict__ Ws2,
    u16* __restrict__ Wt2, u16* __restrict__ Wst2, int ntb) {
    __shared__ union USM {
        struct { float swr[7][1024]; float swn[7][1024]; } r;
        u16 tb[64][256];
    } sm;
    __shared__ int sb0[8], sb1[8];
    __shared__ double sq0[8], sq1[8];
    int bid = blockIdx.x, tid = threadIdx.x;

    if (bid >= 1024) {
        int tbk = bid - 1024;
        if (tbk >= ntb) {                      // ---- init blocks ----
            int gid = (tbk - ntb) * 512 + tid;
            if (gid < NEXP * CPAD) slot_token[gid] = NTOK;
            if (gid < DDIM) zrow[gid] = 0;
            return;
        }
        // ---- transpose block (512 threads, one 256k x 64n tile) ----
        int set = tbk >> 9;                    /* 0 or 1 (ntb=512 when !sep -> always 0) */
        int t9 = tbk & 511;
        int z = t9 >> 6;
        int rem = t9 & 63;
        int k0 = (rem >> 4) * 256;
        int n0 = (rem & 15) * 64;
        const float* srcE = set ? W2 : W1;
        const float* srcS = set ? Ws2 : Ws1;
        u16* dE = set ? Wt2 : Wt;
        u16* dS = set ? Wst2 : Wst;
        const float* src; u16* dst;
        if (z < 7) { src = srcE + (long)z * 1048576; dst = dE + (long)z * 1048576; }
        else       { src = srcS;                     dst = dS; }
#pragma unroll
        for (int p = 0; p < 8; ++p) {
            int kl = p * 32 + (tid >> 4);
            int nl = (tid & 15) * 4;
            float4 v = *(const float4*)(src + (long)(k0 + kl) * 1024 + n0 + nl);
            int s = (tid & 7) << 3;
            int kx = kl ^ s;
            sm.tb[nl + 0][kx] = f2bf(v.x);
            sm.tb[nl + 1][kx] = f2bf(v.y);
            sm.tb[nl + 2][kx] = f2bf(v.z);
            sm.tb[nl + 3][kx] = f2bf(v.w);
        }
        __syncthreads();
#pragma unroll
        for (int q = 0; q < 4; ++q) {
            int nl = q * 16 + (tid >> 5);
            int kl = (tid & 31) * 8;
            int s = ((nl >> 2) & 7) << 3;
            const u16* pr = &sm.tb[nl][kl ^ s];
            ushort4 a = *(const ushort4*)pr;
            ushort4 b = *(const ushort4*)(pr + 4);
            u16* pd = dst + (long)(n0 + nl) * 1024 + k0 + kl;
            *(ushort4*)pd = a;
            *(ushort4*)(pd + 4) = b;
        }
        return;
    }

    // ---- router block ----
    for (int i = tid; i < 7168; i += 512) {
        int d = i / 7, e = i - d * 7;
        sm.r.swr[e][d] = Wr[i];
        sm.r.swn[e][d] = Wn[i];
    }
    __syncthreads();
    int lane = tid & 63, wv = tid >> 6;
    int t = bid * 8 + wv;
    double ar[7] = {0,0,0,0,0,0,0}, an[7] = {0,0,0,0,0,0,0};
#pragma unroll
    for (int j = 0; j < 4; ++j) {
        int d0 = j * 256 + lane * 4;
        float4 xv = *(const float4*)(x + (long)t * 1024 + d0);
        ushort4 o; o.x = f2bf(xv.x); o.y = f2bf(xv.y); o.z = f2bf(xv.z); o.w = f2bf(xv.w);
        *(ushort4*)(xb + (long)t * 1024 + d0) = o;
#pragma unroll
        for (int e = 0; e < 7; ++e) {
            float4 w4 = *(const float4*)&sm.r.swr[e][d0];
            float4 n4 = *(const float4*)&sm.r.swn[e][d0];
            ar[e] += (double)xv.x * (double)w4.x; an[e] += (double)xv.x * (double)n4.x;
            ar[e] += (double)xv.y * (double)w4.y; an[e] += (double)xv.y * (double)n4.y;
            ar[e] += (double)xv.z * (double)w4.z; an[e] += (double)xv.z * (double)n4.z;
            ar[e] += (double)xv.w * (double)w4.w; an[e] += (double)xv.w * (double)n4.w;
        }
    }
#pragma unroll
    for (int e = 0; e < 7; ++e) {
        for (int o = 32; o > 0; o >>= 1) {
            ar[e] += __shfl_xor(ar[e], o);
            an[e] += __shfl_xor(an[e], o);
        }
    }
    if (lane == 0) {
        double best = -1e300, second = -1e300; int b0 = 0, b1 = 0;
#pragma unroll
        for (int e = 0; e < 7; ++e) {
            double lg = ar[e] + (double)br[e];
            double z  = an[e] + (double)bn[e];
            double sp = (z > 30.0) ? (z + log1p(exp(-z))) : log1p(exp(z));
            double v  = lg + (double)noise[t * 7 + e] * sp;
            if (v > best)        { second = best; b1 = b0; best = v; b0 = e; }
            else if (v > second) { second = v; b1 = e; }
        }
        double ex = exp(second - best);
        double q0 = 1.0 / (1.0 + ex);
        double q1 = ex / (1.0 + ex);
        idx0[t] = b0; idx1[t] = b1; p0[t] = (float)q0; p1[t] = (float)q1;
        sb0[wv] = b0; sb1[wv] = b1; sq0[wv] = q0; sq1[wv] = q1;
    }
    __syncthreads();
    if (tid < 7) {
        int c = 0; double s = 0.0;
#pragma unroll
        for (int w = 0; w < 8; ++w) {
            if (sb0[w] == tid) { c++; s += sq0[w]; }
            if (sb1[w] == tid) { c++; s += sq1[w]; }
        }
        cnt8[tid * 1024 + bid] = c;
        sum8[tid * 1024 + bid] = s;
    }
}

// ========== k_scanassign: ONE launch = scan (redundant per block) + FCFS assignment ==========
// 8 blocks x 1024 threads. Each block scans cnt8 (7 x 1024 chunk-8 counts) into LDS base table,
// then assigns its 1024 tokens with chunk-8 ballots. Block 0 additionally writes cnt[] + lbl.
__global__ __launch_bounds__(1024) void k_scanassign(
    const int* __restrict__ cnt8, const double* __restrict__ sum8,
    const int* __restrict__ idx0, const int* __restrict__ idx1,
    int* __restrict__ slot_token, int* __restrict__ ts0, int* __restrict__ ts1,
    int* __restrict__ cnt, float* __restrict__ out) {
    __shared__ int s[7][128];
    __shared__ int b8[7][1024];
    __shared__ double rd[7][128];
    __shared__ int rawc[7];
    int tid = threadIdx.x, bid = blockIdx.x;
    int e = tid >> 7, i = tid & 127;
    bool act = (e < 7);
    int c8[8]; int v = 0;
    if (act) {
#pragma unroll
        for (int j = 0; j < 8; ++j) { c8[j] = cnt8[e * 1024 + i * 8 + j]; v += c8[j]; }
        s[e][i] = v;
        if (bid == 0) {
            double s64 = 0.0;
#pragma unroll
            for (int j = 0; j < 8; ++j) s64 += sum8[e * 1024 + i * 8 + j];
            rd[e][i] = s64;
        }
    }
    __syncthreads();
    for (int o = 1; o < 128; o <<= 1) {
        int add = (act && i >= o) ? s[e][i - o] : 0;
        __syncthreads();
        if (act) s[e][i] += add;
        __syncthreads();
    }
    if (act) {
        int run = s[e][i] - v;
#pragma unroll
        for (int j = 0; j < 8; ++j) { b8[e][i * 8 + j] = run; run += c8[j]; }
        if (i == 127) {
            rawc[e] = s[e][127];
            if (bid == 0) cnt[e] = (s[e][127] < CAPC) ? s[e][127] : CAPC;
        }
    }
    for (int o = 64; o > 0; o >>= 1) {
        if (bid == 0 && act && i < o) rd[e][i] += rd[e][i + o];
        __syncthreads();
    }
    if (bid == 0 && tid == 0) {
        double acc = 0.0;
        for (int ee = 0; ee < 7; ++ee) acc += rd[ee][0] * (double)rawc[ee];
        out[(long)NTOK * DDIM] = (float)(7.0 * acc / (8192.0 * 8192.0));
    }
    __syncthreads();
    // ---- phase 2: assign tokens t = bid*1024 + tid ----
    int t = bid * 1024 + tid;
    int lane = tid & 63;
    int i0 = idx0[t], i1 = idx1[t];
    int myts0 = -1, myts1 = -1;
    unsigned long long gm = 0xFFull << ((lane >> 3) * 8);
    unsigned long long lt = (1ull << lane) - 1ull;
    int chunk = t >> 3;
#pragma unroll
    for (int ee = 0; ee < 7; ++ee) {
        bool has = (i0 == ee) || (i1 == ee);
        unsigned long long m = __ballot(has);
        int pre = __popcll(m & lt & gm);
        int pos = b8[ee][chunk] + pre;
        if (has && pos < CAPC) {
            int slot = ee * CPAD + pos;
            slot_token[slot] = t;
            if (i0 == ee) myts0 = slot; else myts1 = slot;
        }
    }
    ts0[t] = myts0; ts1[t] = myts1;
}

// ---------------- fused MFMA GEMM (round-0 structure + T1 XCD-chunked swizzle) ----------------
// 128x128 tile, BK=64, global_load_lds width-16 staging, 32 KiB LDS -> 3+ blocks/CU.
// Cross-block co-residency hides the staging drain; do NOT add dbuf (r4: -25%).
// T1 swizzle verified r6: FETCH 211->61 MB; GEMM closed (latency/structure-bound).
template <bool GATHER, bool MODE_H>
__global__ __launch_bounds__(256) void k_gemm(
    const u16* __restrict__ AbaseE, const u16* __restrict__ AbaseS,
    const int* __restrict__ gidx, const u16* __restrict__ zrow,
    const u16* __restrict__ WtE, const u16* __restrict__ WtS,
    const float* __restrict__ biasE, const float* __restrict__ biasS,
    u16* __restrict__ outE, u16* __restrict__ outS,
    const int* __restrict__ cnt) {
    __shared__ __align__(16) u16 ldsA[128 * 64];
    __shared__ __align__(16) u16 ldsB[128 * 64];
    int phys = blockIdx.x;
    int bid = (phys & 7) * XCHK + (phys >> 3);   // bijective: TBLK == 8*XCHK
    int tid = threadIdx.x, lane = tid & 63, wv = tid >> 6;
    int lrow = lane >> 3, lkg = lane & 7;
    int kgs = lkg ^ lrow;

    int e = 0, my, nx;
    const u16* Ab; const u16* Bb; const float* bias; u16* outp;
    bool gather = false;
    if (bid < EBLK) {
        e = bid / 168; int r = bid % 168; my = r >> 3; nx = r & 7;
        if (my * 128 >= cnt[e]) return;
        Ab = AbaseE + (GATHER ? 0L : (long)e * CPAD * 1024);
        Bb = WtE + ((long)e << 20);
        bias = biasE + e * 1024;
        outp = outE + (long)e * CPAD * 1024;
        gather = GATHER;
    } else {
        int sb = bid - EBLK; my = sb >> 3; nx = sb & 7;
        Ab = AbaseS; Bb = WtS; bias = biasS; outp = outS;
    }
    int m0 = my * 128, n0 = nx * 128;

    const u16* arow[4];
    const u16* brow[4];
#pragma unroll
    for (int i = 0; i < 4; ++i) {
        int r = (wv * 4 + i) * 8 + lrow;     // 0..127
        if (gather) {
            int tok = gidx[e * CPAD + m0 + r];
            arow[i] = (tok < NTOK) ? (AbaseE + (long)tok * DDIM) : zrow;
        } else {
            arow[i] = Ab + (long)(m0 + r) * DDIM;
        }
        brow[i] = Bb + (long)(n0 + r) * DDIM;
    }
    f32x4 acc[4][4];
#pragma unroll
    for (int a = 0; a < 4; ++a)
#pragma unroll
        for (int b = 0; b < 4; ++b) { f32x4 z = {0.f, 0.f, 0.f, 0.f}; acc[a][b] = z; }

    int wm = (wv >> 1) * 64, wn = (wv & 1) * 64;
    int rl = lane & 15, quad = lane >> 4;

    for (int k0 = 0; k0 < 1024; k0 += 64) {
#pragma unroll
        for (int i = 0; i < 4; ++i) {
            gl2lds16(arow[i] + k0 + kgs * 8, &ldsA[(wv * 4 + i) * 512]);
            gl2lds16(brow[i] + k0 + kgs * 8, &ldsB[(wv * 4 + i) * 512]);
        }
        __syncthreads();   // drains vmcnt -> staged tile visible
#pragma unroll
        for (int ks = 0; ks < 2; ++ks) {
            int kg = ks * 4 + quad;
            bf16x8 af[4], bf[4];
#pragma unroll
            for (int mi = 0; mi < 4; ++mi) {
                int row = wm + mi * 16 + rl;
                af[mi] = *(const bf16x8*)&ldsA[row * 64 + (kg ^ (row & 7)) * 8];
            }
#pragma unroll
            for (int ni = 0; ni < 4; ++ni) {
                int row = wn + ni * 16 + rl;
                bf[ni] = *(const bf16x8*)&ldsB[row * 64 + (kg ^ (row & 7)) * 8];
            }
#pragma unroll
            for (int mi = 0; mi < 4; ++mi)
#pragma unroll
                for (int ni = 0; ni < 4; ++ni)
                    acc[mi][ni] = __builtin_amdgcn_mfma_f32_16x16x32_bf16(
                        af[mi], bf[ni], acc[mi][ni], 0, 0, 0);
        }
        __syncthreads();   // all reads done before next tile overwrites
    }
    // epilogue: C/D layout col = lane&15, row = quad*4 + reg
#pragma unroll
    for (int ni = 0; ni < 4; ++ni) {
        int col = n0 + wn + ni * 16 + rl;
        float bv = bias[col];
#pragma unroll
        for (int mi = 0; mi < 4; ++mi) {
            int rowb = m0 + wm + mi * 16 + quad * 4;
#pragma unroll
            for (int r = 0; r < 4; ++r) {
                float v = acc[mi][ni][r] + bv;
                if constexpr (MODE_H) v = v > 0.f ? v : 0.f;
                outp[(long)(rowb + r) * DDIM + col] = f2bf(v);
            }
        }
    }
}

// ---------------- combine: out = Xs + g0*OutE[s0] + g1*OutE[s1] ----------------
__global__ __launch_bounds__(256) void k_combine(
    const u16* __restrict__ Xs, const u16* __restrict__ OutE,
    const int* __restrict__ ts0, const int* __restrict__ ts1,
    const float* __restrict__ p0, const float* __restrict__ p1,
    float* __restrict__ out) {
    int b = blockIdx.x;
    int d = threadIdx.x * 4;
    long base = (long)b * DDIM + d;
    ushort4 xs4 = *(const ushort4*)(Xs + base);
    float r0 = bf2f(xs4.x), r1 = bf2f(xs4.y), r2 = bf2f(xs4.z), r3 = bf2f(xs4.w);
    int s0 = ts0[b], s1 = ts1[b];
    if (s0 >= 0) {
        float g = p0[b];
        ushort4 o4 = *(const ushort4*)(OutE + (long)s0 * DDIM + d);
        r0 += g * bf2f(o4.x); r1 += g * bf2f(o4.y); r2 += g * bf2f(o4.z); r3 += g * bf2f(o4.w);
    }
    if (s1 >= 0) {
        float g = p1[b];
        ushort4 o4 = *(const ushort4*)(OutE + (long)s1 * DDIM + d);
        r0 += g * bf2f(o4.x); r1 += g * bf2f(o4.y); r2 += g * bf2f(o4.z); r3 += g * bf2f(o4.w);
    }
    float4 w; w.x = r0; w.y = r1; w.z = r2; w.w = r3;
    *(float4*)(out + base) = w;
}

extern "C" void kernel_launch(void* const* d_in, const int* in_sizes, int n_in,
                              void* d_out, int out_size, void* d_ws, size_t ws_size,
                              hipStream_t stream) {
    const float* x    = (const float*)d_in[0];
    const float* noise= (const float*)d_in[1];
    const float* Wr   = (const float*)d_in[2];
    const float* br   = (const float*)d_in[3];
    const float* Wn   = (const float*)d_in[4];
    const float* bn   = (const float*)d_in[5];
    const float* W1   = (const float*)d_in[6];
    const float* b1   = (const float*)d_in[7];
    const float* W2   = (const float*)d_in[8];
    const float* b2   = (const float*)d_in[9];
    const float* Ws1  = (const float*)d_in[10];
    const float* bs1  = (const float*)d_in[11];
    const float* Ws2  = (const float*)d_in[12];
    const float* bs2  = (const float*)d_in[13];
    float* out = (float*)d_out;
    char* ws = (char*)d_ws;

    size_t off = 0;
    auto alloc = [&](size_t bytes) { size_t o = off; off += (bytes + 255) & ~(size_t)255; return o; };
    u16*  Wt   = (u16*)(ws + alloc(7ull * 1048576 * 2));
    u16*  Wst  = (u16*)(ws + alloc(1048576ull * 2));
    u16*  xb   = (u16*)(ws + alloc((size_t)NTOK * 1024 * 2));
    u16*  He   = (u16*)(ws + alloc((size_t)NEXP * CPAD * 1024 * 2));
    u16*  Hs   = (u16*)(ws + alloc((size_t)NTOK * 1024 * 2));
    u16*  OutE = (u16*)(ws + alloc((size_t)NEXP * CPAD * 1024 * 2));
    u16*  Xs   = (u16*)(ws + alloc((size_t)NTOK * 1024 * 2));
    int*  idx0 = (int*)(ws + alloc(NTOK * 4));
    int*  idx1 = (int*)(ws + alloc(NTOK * 4));
    float* p0  = (float*)(ws + alloc(NTOK * 4));
    float* p1  = (float*)(ws + alloc(NTOK * 4));
    int*  ts0  = (int*)(ws + alloc(NTOK * 4));
    int*  ts1  = (int*)(ws + alloc(NTOK * 4));
    int*  slot_token = (int*)(ws + alloc(NEXP * CPAD * 4));
    int*  cnt8  = (int*)(ws + alloc(7 * 1024 * 4));
    double* sum8 = (double*)(ws + alloc(7 * 1024 * 8));
    int*  cnt    = (int*)(ws + alloc(8 * 4));
    u16*  zrow   = (u16*)(ws + alloc(1024 * 2));
    size_t base_off = off;
    // optional separate phase-2 transpose buffers (removes mid-pipeline bubble)
    u16*  Wt2  = (u16*)(ws + alloc(7ull * 1048576 * 2));
    u16*  Wst2 = (u16*)(ws + alloc(1048576ull * 2));

    if (base_off > ws_size) {
        k_zero<<<2048, 256, 0, stream>>>(out, (long)out_size);
        return;
    }
    bool sep = (off <= ws_size);
    if (!sep) { Wt2 = Wt; Wst2 = Wst; }
    int ntb = sep ? 1024 : 512;
    int nib = (NEXP * CPAD + 511) / 512;       /* init blocks: 37 */

    // ONE front launch: router + weight transposes + inits (independent, co-scheduled)
    k_front<<<1024 + ntb + nib, 512, 0, stream>>>(
        x, Wr, Wn, br, bn, noise, xb, idx0, idx1, p0, p1, cnt8, sum8,
        slot_token, zrow, W1, Ws1, Wt, Wst, W2, Ws2, Wt2, Wst2, ntb);

    // ONE scan+assign launch (8 blocks x 1024 thr; block 0 also writes cnt + lbl)
    k_scanassign<<<8, 1024, 0, stream>>>(
        cnt8, sum8, idx0, idx1, slot_token, ts0, ts1, cnt, out);

    // fused layer 1: experts (gather xb via slot_token) + shared, relu -> bf16 He/Hs
    k_gemm<true, true><<<TBLK, 256, 0, stream>>>(
        xb, xb, slot_token, zrow, Wt, Wst, b1, bs1, He, Hs, cnt);

    if (!sep)   // fallback: set1 transpose between the GEMMs
        k_transpose<<<512, 256, 0, stream>>>(W2, Ws2, Wt, Wst);

    // fused layer 2: -> bf16 OutE/Xs (+b2/bs2)
    k_gemm<false, false><<<TBLK, 256, 0, stream>>>(
        He, Hs, nullptr, zrow, Wt2, Wst2, b2, bs2, OutE, Xs, cnt);

    k_combine<<<NTOK, 256, 0, stream>>>(Xs, OutE, ts0, ts1, p0, p1, out);
    (void)in_sizes; (void)n_in; (void)out_size;
}

// Round 9
// 368.465 us; speedup vs baseline: 1.0202x; 1.0202x over previous
//
#include <hip/hip_runtime.h>
#include <math.h>

typedef unsigned short u16;
typedef __attribute__((ext_vector_type(4))) float f32x4;
typedef __bf16 bf16x8 __attribute__((ext_vector_type(8)));

#define NTOK 8192
#define DDIM 1024
#define NEXP 7
#define CAPC 2574      /* int(8192*2/7*1.1) */
#define CPAD 2688      /* 21*128 */
#define EBLK 1176      /* 7 experts * 21 mblk * 8 nblk */
#define TBLK 1688      /* + 64*8 shared blocks; 1688 = 8*211 exactly */
#define XCHK 211       /* blocks per XCD chunk */

__device__ inline float bf2f(u16 u) {
    union { unsigned int i; float f; } c; c.i = ((unsigned int)u) << 16; return c.f;
}
__device__ inline u16 f2bf(float f) {
    union { float f; unsigned int i; } c; c.f = f;
    unsigned int u = c.i;
    unsigned int r = (u + 0x7fffu + ((u >> 16) & 1u)) >> 16;
    return (u16)r;
}

__device__ inline void gl2lds16(const u16* g, const u16* l) {
    __builtin_amdgcn_global_load_lds(
        (const __attribute__((address_space(1))) unsigned int*)g,
        (__attribute__((address_space(3))) unsigned int*)l, 16, 0, 0);
}

// ---------------- guard: zero the output (ws_size-too-small diagnostic) ----------------
__global__ void k_zero(float* out, long n) {
    long i = (long)blockIdx.x * 256 + threadIdx.x;
    long stride = (long)gridDim.x * 256;
    for (; i < n; i += stride) out[i] = 0.f;
}

// ---------------- LDS-tiled transpose core (256 threads; used by !sep fallback) ----------------
__device__ inline void tile_transpose(const float* __restrict__ src, u16* __restrict__ dst,
                                      int k0, int n0, int tid, u16 (*tbuf)[256]) {
#pragma unroll
    for (int p = 0; p < 16; ++p) {
        int kl = p * 16 + (tid >> 4);
        int nl = (tid & 15) * 4;
        float4 v = *(const float4*)(src + (long)(k0 + kl) * 1024 + n0 + nl);
        int s = (tid & 7) << 3;
        int kx = kl ^ s;
        tbuf[nl + 0][kx] = f2bf(v.x);
        tbuf[nl + 1][kx] = f2bf(v.y);
        tbuf[nl + 2][kx] = f2bf(v.z);
        tbuf[nl + 3][kx] = f2bf(v.w);
    }
    __syncthreads();
#pragma unroll
    for (int q = 0; q < 8; ++q) {
        int nl = q * 8 + (tid >> 5);
        int kl = (tid & 31) * 8;
        int s = ((nl >> 2) & 7) << 3;
        const u16* pr = &tbuf[nl][kl ^ s];
        ushort4 a = *(const ushort4*)pr;
        ushort4 b = *(const ushort4*)(pr + 4);
        u16* pd = dst + (long)(n0 + nl) * 1024 + k0 + kl;
        *(ushort4*)pd = a;
        *(ushort4*)(pd + 4) = b;
    }
}

// ---------------- weight transpose phase 2 (fallback when !sep): set1 only ----------------
__global__ void k_transpose(const float* __restrict__ srcE, const float* __restrict__ srcS,
                            u16* __restrict__ Wt, u16* __restrict__ Wst) {
    __shared__ u16 tbuf[64][256];
    int bid = blockIdx.x, tid = threadIdx.x;
    int z = bid >> 6;
    int rem = bid & 63;
    int k0 = (rem >> 4) * 256;
    int n0 = (rem & 15) * 64;
    const float* src; u16* dst;
    if (z < 7) { src = srcE + (long)z * 1048576; dst = Wt + (long)z * 1048576; }
    else       { src = srcS;                     dst = Wst; }
    tile_transpose(src, dst, k0, n0, tid, tbuf);
}

// ========== k_front: ONE launch = router (blocks 0..1023) + weight transposes + inits ==========
// Router restored to the r0-r6 conflict-free pattern (r8 post-mortem: the r7 [e][1024]/float4
// layout caused 1.45e7 LDS bank-conflict cycles):
//   - flat swr[d*7+e]: staging writes tid-consecutive (conflict-free); reads lane-stride 7
//     floats, 7 coprime 32 -> 2 lanes/bank = free.
//   - x read scalar-coalesced once; xb emitted in-loop (keeps the r7 fusion win).
__global__ __launch_bounds__(512) void k_front(
    const float* __restrict__ x,
    const float* __restrict__ Wr, const float* __restrict__ Wn,
    const float* __restrict__ br, const float* __restrict__ bn,
    const float* __restrict__ noise,
    u16* __restrict__ xb,
    int* __restrict__ idx0, int* __restrict__ idx1,
    float* __restrict__ p0, float* __restrict__ p1,
    int* __restrict__ cnt8, double* __restrict__ sum8,
    int* __restrict__ slot_token, u16* __restrict__ zrow,
    const float* __restrict__ W1, const float* __restrict__ Ws1,
    u16* __restrict__ Wt, u16* __restrict__ Wst,
    const float* __restrict__ W2, const float* __restrict__ Ws2,
    u16* __restrict__ Wt2, u16* __restrict__ Wst2, int ntb) {
    __shared__ union USM {
        struct { float swr[7168]; float swn[7168]; } r;
        u16 tb[64][256];
    } sm;
    __shared__ int sb0[8], sb1[8];
    __shared__ double sq0[8], sq1[8];
    int bid = blockIdx.x, tid = threadIdx.x;

    if (bid >= 1024) {
        int tbk = bid - 1024;
        if (tbk >= ntb) {                      // ---- init blocks ----
            int gid = (tbk - ntb) * 512 + tid;
            if (gid < NEXP * CPAD) slot_token[gid] = NTOK;
            if (gid < DDIM) zrow[gid] = 0;
            return;
        }
        // ---- transpose block (512 threads, one 256k x 64n tile) ----
        int set = tbk >> 9;                    /* 0 or 1 (ntb=512 when !sep -> always 0) */
        int t9 = tbk & 511;
        int z = t9 >> 6;
        int rem = t9 & 63;
        int k0 = (rem >> 4) * 256;
        int n0 = (rem & 15) * 64;
        const float* srcE = set ? W2 : W1;
        const float* srcS = set ? Ws2 : Ws1;
        u16* dE = set ? Wt2 : Wt;
        u16* dS = set ? Wst2 : Wst;
        const float* src; u16* dst;
        if (z < 7) { src = srcE + (long)z * 1048576; dst = dE + (long)z * 1048576; }
        else       { src = srcS;                     dst = dS; }
#pragma unroll
        for (int p = 0; p < 8; ++p) {
            int kl = p * 32 + (tid >> 4);
            int nl = (tid & 15) * 4;
            float4 v = *(const float4*)(src + (long)(k0 + kl) * 1024 + n0 + nl);
            int s = (tid & 7) << 3;
            int kx = kl ^ s;
            sm.tb[nl + 0][kx] = f2bf(v.x);
            sm.tb[nl + 1][kx] = f2bf(v.y);
            sm.tb[nl + 2][kx] = f2bf(v.z);
            sm.tb[nl + 3][kx] = f2bf(v.w);
        }
        __syncthreads();
#pragma unroll
        for (int q = 0; q < 4; ++q) {
            int nl = q * 16 + (tid >> 5);
            int kl = (tid & 31) * 8;
            int s = ((nl >> 2) & 7) << 3;
            const u16* pr = &sm.tb[nl][kl ^ s];
            ushort4 a = *(const ushort4*)pr;
            ushort4 b = *(const ushort4*)(pr + 4);
            u16* pd = dst + (long)(n0 + nl) * 1024 + k0 + kl;
            *(ushort4*)pd = a;
            *(ushort4*)(pd + 4) = b;
        }
        return;
    }

    // ---- router block (r0-r6 pattern + xb fusion) ----
    for (int i = tid; i < 7168; i += 512) { sm.r.swr[i] = Wr[i]; sm.r.swn[i] = Wn[i]; }
    __syncthreads();
    int lane = tid & 63, wv = tid >> 6;
    int t = bid * 8 + wv;
    double ar[7] = {0,0,0,0,0,0,0}, an[7] = {0,0,0,0,0,0,0};
    for (int j = 0; j < 16; ++j) {
        int d = j * 64 + lane;
        float xv = x[(long)t * 1024 + d];
        xb[(long)t * 1024 + d] = f2bf(xv);
        double xd = (double)xv;
#pragma unroll
        for (int e = 0; e < 7; ++e) {
            ar[e] += xd * (double)sm.r.swr[d * 7 + e];
            an[e] += xd * (double)sm.r.swn[d * 7 + e];
        }
    }
#pragma unroll
    for (int e = 0; e < 7; ++e) {
        for (int o = 32; o > 0; o >>= 1) {
            ar[e] += __shfl_xor(ar[e], o);
            an[e] += __shfl_xor(an[e], o);
        }
    }
    if (lane == 0) {
        double best = -1e300, second = -1e300; int b0 = 0, b1 = 0;
#pragma unroll
        for (int e = 0; e < 7; ++e) {
            double lg = ar[e] + (double)br[e];
            double z  = an[e] + (double)bn[e];
            double sp = (z > 30.0) ? (z + log1p(exp(-z))) : log1p(exp(z));
            double v  = lg + (double)noise[t * 7 + e] * sp;
            if (v > best)        { second = best; b1 = b0; best = v; b0 = e; }
            else if (v > second) { second = v; b1 = e; }
        }
        double ex = exp(second - best);
        double q0 = 1.0 / (1.0 + ex);
        double q1 = ex / (1.0 + ex);
        idx0[t] = b0; idx1[t] = b1; p0[t] = (float)q0; p1[t] = (float)q1;
        sb0[wv] = b0; sb1[wv] = b1; sq0[wv] = q0; sq1[wv] = q1;
    }
    __syncthreads();
    if (tid < 7) {
        int c = 0; double s = 0.0;
#pragma unroll
        for (int w = 0; w < 8; ++w) {
            if (sb0[w] == tid) { c++; s += sq0[w]; }
            if (sb1[w] == tid) { c++; s += sq1[w]; }
        }
        cnt8[tid * 1024 + bid] = c;
        sum8[tid * 1024 + bid] = s;
    }
}

// ========== k_scanassign: ONE launch = scan (redundant per block) + FCFS assignment ==========
// 8 blocks x 1024 threads. Each block scans cnt8 (7 x 1024 chunk-8 counts) into LDS base table,
// then assigns its 1024 tokens with chunk-8 ballots. Block 0 additionally writes cnt[] + lbl.
__global__ __launch_bounds__(1024) void k_scanassign(
    const int* __restrict__ cnt8, const double* __restrict__ sum8,
    const int* __restrict__ idx0, const int* __restrict__ idx1,
    int* __restrict__ slot_token, int* __restrict__ ts0, int* __restrict__ ts1,
    int* __restrict__ cnt, float* __restrict__ out) {
    __shared__ int s[7][128];
    __shared__ int b8[7][1024];
    __shared__ double rd[7][128];
    __shared__ int rawc[7];
    int tid = threadIdx.x, bid = blockIdx.x;
    int e = tid >> 7, i = tid & 127;
    bool act = (e < 7);
    int c8[8]; int v = 0;
    if (act) {
#pragma unroll
        for (int j = 0; j < 8; ++j) { c8[j] = cnt8[e * 1024 + i * 8 + j]; v += c8[j]; }
        s[e][i] = v;
        if (bid == 0) {
            double s64 = 0.0;
#pragma unroll
            for (int j = 0; j < 8; ++j) s64 += sum8[e * 1024 + i * 8 + j];
            rd[e][i] = s64;
        }
    }
    __syncthreads();
    for (int o = 1; o < 128; o <<= 1) {
        int add = (act && i >= o) ? s[e][i - o] : 0;
        __syncthreads();
        if (act) s[e][i] += add;
        __syncthreads();
    }
    if (act) {
        int run = s[e][i] - v;
#pragma unroll
        for (int j = 0; j < 8; ++j) { b8[e][i * 8 + j] = run; run += c8[j]; }
        if (i == 127) {
            rawc[e] = s[e][127];
            if (bid == 0) cnt[e] = (s[e][127] < CAPC) ? s[e][127] : CAPC;
        }
    }
    for (int o = 64; o > 0; o >>= 1) {
        if (bid == 0 && act && i < o) rd[e][i] += rd[e][i + o];
        __syncthreads();
    }
    if (bid == 0 && tid == 0) {
        double acc = 0.0;
        for (int ee = 0; ee < 7; ++ee) acc += rd[ee][0] * (double)rawc[ee];
        out[(long)NTOK * DDIM] = (float)(7.0 * acc / (8192.0 * 8192.0));
    }
    __syncthreads();
    // ---- phase 2: assign tokens t = bid*1024 + tid ----
    int t = bid * 1024 + tid;
    int lane = tid & 63;
    int i0 = idx0[t], i1 = idx1[t];
    int myts0 = -1, myts1 = -1;
    unsigned long long gm = 0xFFull << ((lane >> 3) * 8);
    unsigned long long lt = (1ull << lane) - 1ull;
    int chunk = t >> 3;
#pragma unroll
    for (int ee = 0; ee < 7; ++ee) {
        bool has = (i0 == ee) || (i1 == ee);
        unsigned long long m = __ballot(has);
        int pre = __popcll(m & lt & gm);
        int pos = b8[ee][chunk] + pre;
        if (has && pos < CAPC) {
            int slot = ee * CPAD + pos;
            slot_token[slot] = t;
            if (i0 == ee) myts0 = slot; else myts1 = slot;
        }
    }
    ts0[t] = myts0; ts1[t] = myts1;
}

// ---------------- fused MFMA GEMM (round-0 structure + T1 XCD-chunked swizzle) ----------------
// 128x128 tile, BK=64, global_load_lds width-16 staging, 32 KiB LDS -> 3+ blocks/CU.
// Cross-block co-residency hides the staging drain; do NOT add dbuf (r4: -25%).
// T1 swizzle verified r6: FETCH 211->61 MB; GEMM closed (latency/structure-bound).
template <bool GATHER, bool MODE_H>
__global__ __launch_bounds__(256) void k_gemm(
    const u16* __restrict__ AbaseE, const u16* __restrict__ AbaseS,
    const int* __restrict__ gidx, const u16* __restrict__ zrow,
    const u16* __restrict__ WtE, const u16* __restrict__ WtS,
    const float* __restrict__ biasE, const float* __restrict__ biasS,
    u16* __restrict__ outE, u16* __restrict__ outS,
    const int* __restrict__ cnt) {
    __shared__ __align__(16) u16 ldsA[128 * 64];
    __shared__ __align__(16) u16 ldsB[128 * 64];
    int phys = blockIdx.x;
    int bid = (phys & 7) * XCHK + (phys >> 3);   // bijective: TBLK == 8*XCHK
    int tid = threadIdx.x, lane = tid & 63, wv = tid >> 6;
    int lrow = lane >> 3, lkg = lane & 7;
    int kgs = lkg ^ lrow;

    int e = 0, my, nx;
    const u16* Ab; const u16* Bb; const float* bias; u16* outp;
    bool gather = false;
    if (bid < EBLK) {
        e = bid / 168; int r = bid % 168; my = r >> 3; nx = r & 7;
        if (my * 128 >= cnt[e]) return;
        Ab = AbaseE + (GATHER ? 0L : (long)e * CPAD * 1024);
        Bb = WtE + ((long)e << 20);
        bias = biasE + e * 1024;
        outp = outE + (long)e * CPAD * 1024;
        gather = GATHER;
    } else {
        int sb = bid - EBLK; my = sb >> 3; nx = sb & 7;
        Ab = AbaseS; Bb = WtS; bias = biasS; outp = outS;
    }
    int m0 = my * 128, n0 = nx * 128;

    const u16* arow[4];
    const u16* brow[4];
#pragma unroll
    for (int i = 0; i < 4; ++i) {
        int r = (wv * 4 + i) * 8 + lrow;     // 0..127
        if (gather) {
            int tok = gidx[e * CPAD + m0 + r];
            arow[i] = (tok < NTOK) ? (AbaseE + (long)tok * DDIM) : zrow;
        } else {
            arow[i] = Ab + (long)(m0 + r) * DDIM;
        }
        brow[i] = Bb + (long)(n0 + r) * DDIM;
    }
    f32x4 acc[4][4];
#pragma unroll
    for (int a = 0; a < 4; ++a)
#pragma unroll
        for (int b = 0; b < 4; ++b) { f32x4 z = {0.f, 0.f, 0.f, 0.f}; acc[a][b] = z; }

    int wm = (wv >> 1) * 64, wn = (wv & 1) * 64;
    int rl = lane & 15, quad = lane >> 4;

    for (int k0 = 0; k0 < 1024; k0 += 64) {
#pragma unroll
        for (int i = 0; i < 4; ++i) {
            gl2lds16(arow[i] + k0 + kgs * 8, &ldsA[(wv * 4 + i) * 512]);
            gl2lds16(brow[i] + k0 + kgs * 8, &ldsB[(wv * 4 + i) * 512]);
        }
        __syncthreads();   // drains vmcnt -> staged tile visible
#pragma unroll
        for (int ks = 0; ks < 2; ++ks) {
            int kg = ks * 4 + quad;
            bf16x8 af[4], bf[4];
#pragma unroll
            for (int mi = 0; mi < 4; ++mi) {
                int row = wm + mi * 16 + rl;
                af[mi] = *(const bf16x8*)&ldsA[row * 64 + (kg ^ (row & 7)) * 8];
            }
#pragma unroll
            for (int ni = 0; ni < 4; ++ni) {
                int row = wn + ni * 16 + rl;
                bf[ni] = *(const bf16x8*)&ldsB[row * 64 + (kg ^ (row & 7)) * 8];
            }
#pragma unroll
            for (int mi = 0; mi < 4; ++mi)
#pragma unroll
                for (int ni = 0; ni < 4; ++ni)
                    acc[mi][ni] = __builtin_amdgcn_mfma_f32_16x16x32_bf16(
                        af[mi], bf[ni], acc[mi][ni], 0, 0, 0);
        }
        __syncthreads();   // all reads done before next tile overwrites
    }
    // epilogue: C/D layout col = lane&15, row = quad*4 + reg
#pragma unroll
    for (int ni = 0; ni < 4; ++ni) {
        int col = n0 + wn + ni * 16 + rl;
        float bv = bias[col];
#pragma unroll
        for (int mi = 0; mi < 4; ++mi) {
            int rowb = m0 + wm + mi * 16 + quad * 4;
#pragma unroll
            for (int r = 0; r < 4; ++r) {
                float v = acc[mi][ni][r] + bv;
                if constexpr (MODE_H) v = v > 0.f ? v : 0.f;
                outp[(long)(rowb + r) * DDIM + col] = f2bf(v);
            }
        }
    }
}

// ---------------- combine: out = Xs + g0*OutE[s0] + g1*OutE[s1] ----------------
__global__ __launch_bounds__(256) void k_combine(
    const u16* __restrict__ Xs, const u16* __restrict__ OutE,
    const int* __restrict__ ts0, const int* __restrict__ ts1,
    const float* __restrict__ p0, const float* __restrict__ p1,
    float* __restrict__ out) {
    int b = blockIdx.x;
    int d = threadIdx.x * 4;
    long base = (long)b * DDIM + d;
    ushort4 xs4 = *(const ushort4*)(Xs + base);
    float r0 = bf2f(xs4.x), r1 = bf2f(xs4.y), r2 = bf2f(xs4.z), r3 = bf2f(xs4.w);
    int s0 = ts0[b], s1 = ts1[b];
    if (s0 >= 0) {
        float g = p0[b];
        ushort4 o4 = *(const ushort4*)(OutE + (long)s0 * DDIM + d);
        r0 += g * bf2f(o4.x); r1 += g * bf2f(o4.y); r2 += g * bf2f(o4.z); r3 += g * bf2f(o4.w);
    }
    if (s1 >= 0) {
        float g = p1[b];
        ushort4 o4 = *(const ushort4*)(OutE + (long)s1 * DDIM + d);
        r0 += g * bf2f(o4.x); r1 += g * bf2f(o4.y); r2 += g * bf2f(o4.z); r3 += g * bf2f(o4.w);
    }
    float4 w; w.x = r0; w.y = r1; w.z = r2; w.w = r3;
    *(float4*)(out + base) = w;
}

extern "C" void kernel_launch(void* const* d_in, const int* in_sizes, int n_in,
                              void* d_out, int out_size, void* d_ws, size_t ws_size,
                              hipStream_t stream) {
    const float* x    = (const float*)d_in[0];
    const float* noise= (const float*)d_in[1];
    const float* Wr   = (const float*)d_in[2];
    const float* br   = (const float*)d_in[3];
    const float* Wn   = (const float*)d_in[4];
    const float* bn   = (const float*)d_in[5];
    const float* W1   = (const float*)d_in[6];
    const float* b1   = (const float*)d_in[7];
    const float* W2   = (const float*)d_in[8];
    const float* b2   = (const float*)d_in[9];
    const float* Ws1  = (const float*)d_in[10];
    const float* bs1  = (const float*)d_in[11];
    const float* Ws2  = (const float*)d_in[12];
    const float* bs2  = (const float*)d_in[13];
    float* out = (float*)d_out;
    char* ws = (char*)d_ws;

    size_t off = 0;
    auto alloc = [&](size_t bytes) { size_t o = off; off += (bytes + 255) & ~(size_t)255; return o; };
    u16*  Wt   = (u16*)(ws + alloc(7ull * 1048576 * 2));
    u16*  Wst  = (u16*)(ws + alloc(1048576ull * 2));
    u16*  xb   = (u16*)(ws + alloc((size_t)NTOK * 1024 * 2));
    u16*  He   = (u16*)(ws + alloc((size_t)NEXP * CPAD * 1024 * 2));
    u16*  Hs   = (u16*)(ws + alloc((size_t)NTOK * 1024 * 2));
    u16*  OutE = (u16*)(ws + alloc((size_t)NEXP * CPAD * 1024 * 2));
    u16*  Xs   = (u16*)(ws + alloc((size_t)NTOK * 1024 * 2));
    int*  idx0 = (int*)(ws + alloc(NTOK * 4));
    int*  idx1 = (int*)(ws + alloc(NTOK * 4));
    float* p0  = (float*)(ws + alloc(NTOK * 4));
    float* p1  = (float*)(ws + alloc(NTOK * 4));
    int*  ts0  = (int*)(ws + alloc(NTOK * 4));
    int*  ts1  = (int*)(ws + alloc(NTOK * 4));
    int*  slot_token = (int*)(ws + alloc(NEXP * CPAD * 4));
    int*  cnt8  = (int*)(ws + alloc(7 * 1024 * 4));
    double* sum8 = (double*)(ws + alloc(7 * 1024 * 8));
    int*  cnt    = (int*)(ws + alloc(8 * 4));
    u16*  zrow   = (u16*)(ws + alloc(1024 * 2));
    size_t base_off = off;
    // optional separate phase-2 transpose buffers (removes mid-pipeline bubble)
    u16*  Wt2  = (u16*)(ws + alloc(7ull * 1048576 * 2));
    u16*  Wst2 = (u16*)(ws + alloc(1048576ull * 2));

    if (base_off > ws_size) {
        k_zero<<<2048, 256, 0, stream>>>(out, (long)out_size);
        return;
    }
    bool sep = (off <= ws_size);
    if (!sep) { Wt2 = Wt; Wst2 = Wst; }
    int ntb = sep ? 1024 : 512;
    int nib = (NEXP * CPAD + 511) / 512;       /* init blocks: 37 */

    // ONE front launch: router + weight transposes + inits (independent, co-scheduled)
    k_front<<<1024 + ntb + nib, 512, 0, stream>>>(
        x, Wr, Wn, br, bn, noise, xb, idx0, idx1, p0, p1, cnt8, sum8,
        slot_token, zrow, W1, Ws1, Wt, Wst, W2, Ws2, Wt2, Wst2, ntb);

    // ONE scan+assign launch (8 blocks x 1024 thr; block 0 also writes cnt + lbl)
    k_scanassign<<<8, 1024, 0, stream>>>(
        cnt8, sum8, idx0, idx1, slot_token, ts0, ts1, cnt, out);

    // fused layer 1: experts (gather xb via slot_token) + shared, relu -> bf16 He/Hs
    k_gemm<true, true><<<TBLK, 256, 0, stream>>>(
        xb, xb, slot_token, zrow, Wt, Wst, b1, bs1, He, Hs, cnt);

    if (!sep)   // fallback: set1 transpose between the GEMMs
        k_transpose<<<512, 256, 0, stream>>>(W2, Ws2, Wt, Wst);

    // fused layer 2: -> bf16 OutE/Xs (+b2/bs2)
    k_gemm<false, false><<<TBLK, 256, 0, stream>>>(
        He, Hs, nullptr, zrow, Wt2, Wst2, b2, bs2, OutE, Xs, cnt);

    k_combine<<<NTOK, 256, 0, stream>>>(Xs, OutE, ts0, ts1, p0, p1, out);
    (void)in_sizes; (void)n_in; (void)out_size;
}